// Round 2
// baseline (335.170 us; speedup 1.0000x reference)
//
#include <hip/hip_runtime.h>

#define T_IN   1048576
#define T_OUT  1048564              // T_IN - 12
#define ROWS   32                   // 8 * 4
#define QPR    262141               // quads per output row (T_OUT/4, odd!)
#define SPR    65536                // thread slots per row (power of 2, no div needed)

// Each thread handles 4 output quads in its row at slot, slot+65536, slot+131072,
// slot+196608. 4*65536 = 262144 >= 262141, so only k=3 needs a bounds check
// (slots 65533..65535 skip it). All 16 float4 loads are issued before any
// consuming FMA -> ~16 KB in flight per wave (fixes the 32-VGPR latency trap
// of R0: compiler had serialized loads to fit 32 regs).
__global__ __launch_bounds__(256, 4) void pinn_fused_conv13(
    const float* __restrict__ x,
    const float* __restrict__ fd,     // 5 taps (already scaled by 1/h^2)
    const float* __restrict__ gs,     // 9 taps
    float* __restrict__ out)
{
    const int tid = blockIdx.x * 256 + threadIdx.x;
    const int r = tid >> 16;          // row 0..31
    const int s = tid & 65535;        // slot in row

    const float* __restrict__ xrow = x + (size_t)r * T_IN;
    float* __restrict__ orow = out + (size_t)r * T_OUT;

    const int t0 = s * 4;             // output/input offsets, all 16B-aligned
    const int t1 = t0 + SPR * 4;
    const int t2 = t1 + SPR * 4;
    const int t3 = t2 + SPR * 4;
    const bool ok3 = (s + 3 * SPR) < QPR;   // false only for s>=65533

    // ---- issue all loads first (16 dwordx4 in flight) ----
    float4 v[4][4];
#pragma unroll
    for (int i = 0; i < 4; ++i) v[0][i] = *reinterpret_cast<const float4*>(xrow + t0 + 4 * i);
#pragma unroll
    for (int i = 0; i < 4; ++i) v[1][i] = *reinterpret_cast<const float4*>(xrow + t1 + 4 * i);
#pragma unroll
    for (int i = 0; i < 4; ++i) v[2][i] = *reinterpret_cast<const float4*>(xrow + t2 + 4 * i);
    float4 v3_[4];
    if (ok3) {
#pragma unroll
        for (int i = 0; i < 4; ++i) v3_[i] = *reinterpret_cast<const float4*>(xrow + t3 + 4 * i);
    } else {
#pragma unroll
        for (int i = 0; i < 4; ++i) v3_[i] = make_float4(0.f, 0.f, 0.f, 0.f);
    }
#pragma unroll
    for (int i = 0; i < 4; ++i) v[3][i] = v3_[i];

    // ---- compose the 13-tap kernel: c[k] = sum_{i+j=k} fd[i]*gs[j] ----
    float f[5], g[9], c[13];
#pragma unroll
    for (int k = 0; k < 13; ++k) c[k] = 0.0f;
#pragma unroll
    for (int i = 0; i < 5; ++i) f[i] = fd[i];
#pragma unroll
    for (int j = 0; j < 9; ++j) g[j] = gs[j];
#pragma unroll
    for (int i = 0; i < 5; ++i)
#pragma unroll
        for (int j = 0; j < 9; ++j) c[i + j] = fmaf(f[i], g[j], c[i + j]);

    // ---- compute 4 outputs per quad, store ----
    const int ts[4] = {t0, t1, t2, t3};
#pragma unroll
    for (int k = 0; k < 4; ++k) {
        float a[16] = {v[k][0].x, v[k][0].y, v[k][0].z, v[k][0].w,
                       v[k][1].x, v[k][1].y, v[k][1].z, v[k][1].w,
                       v[k][2].x, v[k][2].y, v[k][2].z, v[k][2].w,
                       v[k][3].x, v[k][3].y, v[k][3].z, v[k][3].w};
        float o[4];
#pragma unroll
        for (int j = 0; j < 4; ++j) {
            float sacc = 0.0f;
#pragma unroll
            for (int t = 0; t < 13; ++t) sacc = fmaf(c[t], a[j + t], sacc);
            o[j] = sacc;
        }
        if (k < 3 || ok3) {
            *reinterpret_cast<float4*>(orow + ts[k]) = make_float4(o[0], o[1], o[2], o[3]);
        }
    }
}

extern "C" void kernel_launch(void* const* d_in, const int* in_sizes, int n_in,
                              void* d_out, int out_size, void* d_ws, size_t ws_size,
                              hipStream_t stream) {
    const float* x  = (const float*)d_in[0];
    const float* fd = (const float*)d_in[1];
    const float* gs = (const float*)d_in[2];
    float* out = (float*)d_out;

    // 32 rows * 65536 slots = 2,097,152 threads = 8192 blocks x 256, no loop.
    pinn_fused_conv13<<<8192, 256, 0, stream>>>(x, fd, gs, out);
}

// Round 3
// 221.529 us; speedup vs baseline: 1.5130x; 1.5130x over previous
//
#include <hip/hip_runtime.h>

#define T_IN   1048576
#define T_OUT  1048564              // T_IN - 12 (valid 5-tap then valid 9-tap)
#define QPR    262141               // output quads per row (T_OUT/4)
#define BPR    1024                 // blocks per row (1024*256 = 262144 >= QPR)

// One float4 output quad per thread, LDS-staged input tile.
// Global side is copy-shaped: each thread does exactly one float4 load and
// (at most) one float4 store, perfectly coalesced, no overlap re-reads.
// Halo sharing goes through LDS (1040 floats/block, consecutive-16B b128
// reads -> no bank conflicts).
__global__ __launch_bounds__(256) void pinn_fused_conv13(
    const float* __restrict__ x,
    const float* __restrict__ fd,     // 5 taps (already scaled by 1/h^2)
    const float* __restrict__ gs,     // 9 taps
    float* __restrict__ out)
{
    __shared__ float lds[1040];       // 256*4 main + 16 halo

    const int r  = blockIdx.x >> 10;        // row 0..31
    const int b  = blockIdx.x & (BPR - 1);  // block-in-row
    const int t  = threadIdx.x;
    const int qb = b << 8;                  // first quad of this block
    const int in0 = qb << 2;                // first input float of this block

    const float* __restrict__ xrow = x + (size_t)r * T_IN;
    float* __restrict__ orow = out + (size_t)r * T_OUT;

    // ---- global -> LDS staging (1:1, coalesced) ----
    const float4 mv = *reinterpret_cast<const float4*>(xrow + in0 + 4 * t);
    float4 hv = make_float4(0.f, 0.f, 0.f, 0.f);
    const bool is_halo = (t < 4);
    // halo floats [in0+1024, in0+1040): out of bounds only for b == 1023,
    // where those values are never consumed (last block has 253 active quads).
    if (is_halo && (in0 + 1024 + 4 * t + 4 <= T_IN)) {
        hv = *reinterpret_cast<const float4*>(xrow + in0 + 1024 + 4 * t);
    }

    // ---- compose 13-tap kernel while loads are in flight ----
    // c[k] = sum_{i+j=k} fd[i]*gs[j]
    float f[5], g[9], c[13];
#pragma unroll
    for (int k = 0; k < 13; ++k) c[k] = 0.0f;
#pragma unroll
    for (int i = 0; i < 5; ++i) f[i] = fd[i];
#pragma unroll
    for (int j = 0; j < 9; ++j) g[j] = gs[j];
#pragma unroll
    for (int i = 0; i < 5; ++i)
#pragma unroll
        for (int j = 0; j < 9; ++j) c[i + j] = fmaf(f[i], g[j], c[i + j]);

    *reinterpret_cast<float4*>(lds + 4 * t) = mv;
    if (is_halo) *reinterpret_cast<float4*>(lds + 1024 + 4 * t) = hv;
    __syncthreads();

    // ---- compute 4 outputs from lds[4t .. 4t+15] ----
    const int q = qb + t;
    if (q < QPR) {
        // first 16B already in registers (own staging load); read the rest
        const float4 w1 = *reinterpret_cast<const float4*>(lds + 4 * t + 4);
        const float4 w2 = *reinterpret_cast<const float4*>(lds + 4 * t + 8);
        const float4 w3 = *reinterpret_cast<const float4*>(lds + 4 * t + 12);

        const float a[16] = {mv.x, mv.y, mv.z, mv.w,
                             w1.x, w1.y, w1.z, w1.w,
                             w2.x, w2.y, w2.z, w2.w,
                             w3.x, w3.y, w3.z, w3.w};
        float o[4];
#pragma unroll
        for (int j = 0; j < 4; ++j) {
            float s = 0.0f;
#pragma unroll
            for (int k = 0; k < 13; ++k) s = fmaf(c[k], a[j + k], s);
            o[j] = s;
        }
        *reinterpret_cast<float4*>(orow + 4 * q) =
            make_float4(o[0], o[1], o[2], o[3]);
    }
}

extern "C" void kernel_launch(void* const* d_in, const int* in_sizes, int n_in,
                              void* d_out, int out_size, void* d_ws, size_t ws_size,
                              hipStream_t stream) {
    const float* x  = (const float*)d_in[0];
    const float* fd = (const float*)d_in[1];
    const float* gs = (const float*)d_in[2];
    float* out = (float*)d_out;

    // 32 rows x 1024 blocks/row = 32768 blocks of 256 threads.
    pinn_fused_conv13<<<32 * BPR, 256, 0, stream>>>(x, fd, gs, out);
}